// Round 14
// baseline (10428.631 us; speedup 1.0000x reference)
//
#include <hip/hip_runtime.h>
#include <math.h>

#define NV      50000
#define T_STEPS 1023
#define KDIM    1024
typedef unsigned long long ull;

#define NRECUR  64
#define NEW_    16
#define NLW     147
#define NBLK    (NRECUR + NEW_ + NLW)   // 227
#define ERING   512
#define NSTRIPE 391                     // 391 x 128 cols = 50048 >= NV
#define NBATCH  8                       // 8 x 128 steps = 1024 >= T_STEPS
#define BSTEP   128                     // steps per batch (16 per wave)
#define TSB     24576                   // GI row bytes = per-step cand stride
#define CANDI_OFF 6272
#define NCAND   1564                    // 2 * 782 chunks of 64 cols

// ws layout (bytes):
//   [0,16K)        SA ull[2][1024]     [16K,32K)  SB ull[2][1024]
//   [32K,+512)     done int[2][64]     [33280,+256) prog int[64]
//   [33536,+4K)    Edone int[1024]     [37632,+64)  bcount int[8]
//   [40960,+4K)    Psum f32[1024]      [45056,+4K)  Ttgt f32[1024]
//   [96K, +24M)    GI f64[1024][3072]; row s holds cand[s] once dead
//   [96K+24M,+4M)  X f32[1024][1024], then Ering f64[512][1024]
//   [96K+28M,+8M)  H f64[1024][1024]
// total ~36.09 MiB

// ---------------------------------------------------------------- gather ----
__global__ __launch_bounds__(256) void k_gather(const int* __restrict__ inputs,
                                                const float* __restrict__ emb,
                                                float* __restrict__ X) {
  const int t = blockIdx.x;
  const int tid = threadIdx.x;
  float4 v = make_float4(0.f, 0.f, 0.f, 0.f);
  if (t < T_STEPS) {
    const int tok = (t == 0) ? 0 : inputs[t];
    v = *(const float4*)&emb[(size_t)tok * KDIM + tid * 4];
  }
  *(float4*)&X[(size_t)t * KDIM + tid * 4] = v;
}

// ---------------- NT GEMM: A f32 x B f32 -> C f64, fp64 accumulate ----------
__global__ __launch_bounds__(256) void k_gemm_ffd(const float* __restrict__ A,
                                                  const float* __restrict__ B,
                                                  const float* __restrict__ bias,
                                                  double* __restrict__ C,
                                                  int N, int K) {
  __shared__ float As[32][68];
  __shared__ float Bs[32][68];
  const int tid = threadIdx.x;
  const int bx = blockIdx.x, by = blockIdx.y;
  const int lr = tid >> 2;
  const int lk = (tid & 3) * 8;
  const float* Ap = A + (size_t)(by * 64 + lr) * K + lk;
  const float* Bp = B + (size_t)(bx * 64 + lr) * K + lk;
  const int r0 = (tid >> 4) * 4;
  const int c0 = (tid & 15) * 4;
  double acc[4][4] = {};
  for (int kc = 0; kc < K; kc += 32) {
    const float4 a0 = *(const float4*)(Ap + kc);
    const float4 a1 = *(const float4*)(Ap + kc + 4);
    const float4 b0 = *(const float4*)(Bp + kc);
    const float4 b1 = *(const float4*)(Bp + kc + 4);
    __syncthreads();
    As[lk+0][lr]=a0.x; As[lk+1][lr]=a0.y; As[lk+2][lr]=a0.z; As[lk+3][lr]=a0.w;
    As[lk+4][lr]=a1.x; As[lk+5][lr]=a1.y; As[lk+6][lr]=a1.z; As[lk+7][lr]=a1.w;
    Bs[lk+0][lr]=b0.x; Bs[lk+1][lr]=b0.y; Bs[lk+2][lr]=b0.z; Bs[lk+3][lr]=b0.w;
    Bs[lk+4][lr]=b1.x; Bs[lk+5][lr]=b1.y; Bs[lk+6][lr]=b1.z; Bs[lk+7][lr]=b1.w;
    __syncthreads();
#pragma unroll
    for (int kk = 0; kk < 32; ++kk) {
      const float4 av = *(const float4*)&As[kk][r0];
      const float4 bv = *(const float4*)&Bs[kk][c0];
      const double aa[4] = {av.x, av.y, av.z, av.w};
      const double bb[4] = {bv.x, bv.y, bv.z, bv.w};
#pragma unroll
      for (int i = 0; i < 4; ++i)
#pragma unroll
        for (int j = 0; j < 4; ++j)
          acc[i][j] = fma(aa[i], bb[j], acc[i][j]);
    }
  }
  const int row = by * 64 + r0;
  const int col = bx * 64 + c0;
#pragma unroll
  for (int i = 0; i < 4; ++i)
#pragma unroll
    for (int j = 0; j < 4; ++j)
      C[(size_t)(row + i) * N + col + j] = acc[i][j] + (double)bias[col + j];
}

// ------------- mega kernel: recur + E-workers + logits workers --------------
__global__ __launch_bounds__(512, 1) void k_mega(
    const float* z, const float* Whh, const float* bhh,
    const double* GI, double* H, ull* SA, ull* SB, int* done,
    int* prog, int* Edone, int* bcount, double* Ering,
    const float* h2eW, const float* h2eb,
    const float* emb, const float* out_b, const int* inputs,
    float* Psum, float* Ttgt, char* candb)
{
  __shared__ double SM[4096];     // recur/E: h row (1024); lworker: E tile
  const int tid = threadIdx.x;
  const int bid = blockIdx.x;

  if (bid < NRECUR) {
    // ================= recur role (r9 protocol + prog publish) =============
    double* hs = SM;
    const int w = tid >> 6, l = tid & 63;
    const int ibase = bid * 16 + w * 2;
    float wreg[6][16];
#pragma unroll
    for (int il = 0; il < 2; ++il)
#pragma unroll
      for (int g = 0; g < 3; ++g) {
        const float* wp = Whh + (size_t)(g * 1024 + ibase + il) * 1024 + l;
#pragma unroll
        for (int m = 0; m < 16; ++m) wreg[il * 3 + g][m] = wp[m * 64];
      }
    double bh[6];
#pragma unroll
    for (int il = 0; il < 2; ++il)
#pragma unroll
      for (int g = 0; g < 3; ++g) bh[il * 3 + g] = (double)bhh[g * 1024 + ibase + il];

    hs[tid]       = (double)z[tid];
    hs[tid + 512] = (double)z[tid + 512];
    double gi[6];
#pragma unroll
    for (int il = 0; il < 2; ++il)
#pragma unroll
      for (int g = 0; g < 3; ++g) gi[il * 3 + g] = GI[g * 1024 + ibase + il];
    __syncthreads();

    for (int t = 0; t < T_STEPS; ++t) {
      const bool more = (t + 1 < T_STEPS);
      const int p = t & 1;
      const bool gate = more && (t >= 2);
      int dv = 0x7FFFFFFF;
      if (gate && tid < 64)
        dv = __hip_atomic_load(done + p * 64 + tid,
                               __ATOMIC_RELAXED, __HIP_MEMORY_SCOPE_AGENT);
      double s[6] = {0.0, 0.0, 0.0, 0.0, 0.0, 0.0};
#pragma unroll
      for (int m = 0; m < 16; ++m) {
        const double hv = hs[l + 64 * m];
#pragma unroll
        for (int rr = 0; rr < 6; ++rr) s[rr] = fma((double)wreg[rr][m], hv, s[rr]);
      }
#pragma unroll
      for (int rr = 0; rr < 6; ++rr) {
        double v = s[rr];
#pragma unroll
        for (int mk = 32; mk >= 1; mk >>= 1) v += __shfl_xor(v, mk, 64);
        s[rr] = v;
      }
      double hn = 0.0;
      if (l < 2) {
        const int il = l;
        const double r  = 1.0 / (1.0 + exp(-(gi[il*3+0] + s[il*3+0] + bh[il*3+0])));
        const double zg = 1.0 / (1.0 + exp(-(gi[il*3+1] + s[il*3+1] + bh[il*3+1])));
        const double n  = tanh(gi[il*3+2] + r * (s[il*3+2] + bh[il*3+2]));
        hn = (1.0 - zg) * n + zg * hs[ibase + l];
      }
      double gin[6] = {0.0, 0.0, 0.0, 0.0, 0.0, 0.0};
      if (more) {
        const double* gp = GI + (size_t)(t + 1) * 3072;
#pragma unroll
        for (int il = 0; il < 2; ++il)
#pragma unroll
          for (int g = 0; g < 3; ++g) gin[il * 3 + g] = gp[g * 1024 + ibase + il];
      }
      if (gate && tid < 64) {
        while (!__all(dv >= t - 1)) {
          __builtin_amdgcn_s_sleep(1);
          dv = __hip_atomic_load(done + p * 64 + tid,
                                 __ATOMIC_RELAXED, __HIP_MEMORY_SCOPE_AGENT);
        }
      }
      __syncthreads();
      if (l < 2) {
        const int gidx = ibase + l;
        __hip_atomic_store(H + (size_t)t * 1024 + gidx, hn,
                           __ATOMIC_RELAXED, __HIP_MEMORY_SCOPE_AGENT);
        if (more) {
          const ull hb  = (ull)__double_as_longlong(hn);
          const ull tag = ((ull)(t + 1)) << 32;
          __hip_atomic_store(SA + p * 1024 + gidx, tag | (hb >> 32),
                             __ATOMIC_RELAXED, __HIP_MEMORY_SCOPE_AGENT);
          __hip_atomic_store(SB + p * 1024 + gidx, tag | (hb & 0xFFFFFFFFull),
                             __ATOMIC_RELAXED, __HIP_MEMORY_SCOPE_AGENT);
        }
      }
      if (more) {
        const ull want = (ull)(t + 1);
        ull a0, b0, a1, b1;
        while (true) {
          a0 = __hip_atomic_load(SA + p * 1024 + tid,
                                 __ATOMIC_RELAXED, __HIP_MEMORY_SCOPE_AGENT);
          b0 = __hip_atomic_load(SB + p * 1024 + tid,
                                 __ATOMIC_RELAXED, __HIP_MEMORY_SCOPE_AGENT);
          if ((a0 >> 32) >= want && (b0 >> 32) >= want) break;
          __builtin_amdgcn_s_sleep(1);
        }
        while (true) {
          a1 = __hip_atomic_load(SA + p * 1024 + tid + 512,
                                 __ATOMIC_RELAXED, __HIP_MEMORY_SCOPE_AGENT);
          b1 = __hip_atomic_load(SB + p * 1024 + tid + 512,
                                 __ATOMIC_RELAXED, __HIP_MEMORY_SCOPE_AGENT);
          if ((a1 >> 32) >= want && (b1 >> 32) >= want) break;
          __builtin_amdgcn_s_sleep(1);
        }
        hs[tid]       = __longlong_as_double((long long)
                          (((a0 & 0xFFFFFFFFull) << 32) | (b0 & 0xFFFFFFFFull)));
        hs[tid + 512] = __longlong_as_double((long long)
                          (((a1 & 0xFFFFFFFFull) << 32) | (b1 & 0xFFFFFFFFull)));
        __syncthreads();   // every wave drained its own H/SA/SB stores here
        if (tid == 0) {
          __hip_atomic_store(done + p * 64 + bid, t + 1,
                             __ATOMIC_RELAXED, __HIP_MEMORY_SCOPE_AGENT);
          __hip_atomic_store(prog + bid, t + 1,
                             __ATOMIC_RELAXED, __HIP_MEMORY_SCOPE_AGENT);
        }
#pragma unroll
        for (int q = 0; q < 6; ++q) gi[q] = gin[q];
      }
    }
    __syncthreads();       // drain final H stores
    if (tid == 0)
      __hip_atomic_store(prog + bid, T_STEPS,
                         __ATOMIC_RELAXED, __HIP_MEMORY_SCOPE_AGENT);

  } else if (bid < NRECUR + NEW_) {
    // ================= E worker: E[s] = h2eW @ h[s] + h2eb =================
    const int e = bid - NRECUR;
    for (int s = e; s < T_STEPS; s += NEW_) {
      if (s >= ERING && tid == 0) {
        const int bi = (s - ERING) >> 7;   // batch whose data occupied slot
        while (__hip_atomic_load(bcount + bi, __ATOMIC_RELAXED,
                                 __HIP_MEMORY_SCOPE_AGENT) < NSTRIPE)
          __builtin_amdgcn_s_sleep(8);
      }
      if (tid < 64) {
        while (true) {
          const int pv = __hip_atomic_load(prog + tid, __ATOMIC_RELAXED,
                                           __HIP_MEMORY_SCOPE_AGENT);
          if (__all(pv >= s + 1)) break;
          __builtin_amdgcn_s_sleep(8);
        }
      }
      __syncthreads();
      SM[tid]       = __hip_atomic_load(H + (size_t)s * 1024 + tid,
                        __ATOMIC_RELAXED, __HIP_MEMORY_SCOPE_AGENT);
      SM[tid + 512] = __hip_atomic_load(H + (size_t)s * 1024 + tid + 512,
                        __ATOMIC_RELAXED, __HIP_MEMORY_SCOPE_AGENT);
      __syncthreads();
      double a0 = 0.0, a1 = 0.0;
      const float* w0 = h2eW + (size_t)tid * 1024;
      const float* w1 = h2eW + (size_t)(tid + 512) * 1024;
      for (int k = 0; k < 1024; ++k) {        // ascending k: bit-identical
        const double hv = SM[k];
        a0 = fma((double)w0[k], hv, a0);
        a1 = fma((double)w1[k], hv, a1);
      }
      double* er = Ering + (size_t)(s & (ERING - 1)) * 1024;
      __hip_atomic_store(er + tid, a0 + (double)h2eb[tid],
                         __ATOMIC_RELAXED, __HIP_MEMORY_SCOPE_AGENT);
      __hip_atomic_store(er + tid + 512, a1 + (double)h2eb[tid + 512],
                         __ATOMIC_RELAXED, __HIP_MEMORY_SCOPE_AGENT);
      __syncthreads();     // all E stores drained
      if (tid == 0)
        __hip_atomic_store(Edone + s, 1,
                           __ATOMIC_RELAXED, __HIP_MEMORY_SCOPE_AGENT);
    }

  } else {
    // ====== logits worker: units of (128-step batch x 128-col stripe) ======
    // E tile [kj][si] (32 x 128 doubles = 32 KB) shared by all 8 waves;
    // emb streamed from global (each col row read ONCE per 128 steps).
    const int wk = bid - NRECUR - NEW_;       // 0..146
    const int wv = tid >> 6, lane = tid & 63;
    for (int u = wk; u < NBATCH * NSTRIPE; u += NLW) {
      const int b = u / NSTRIPE, j = u - b * NSTRIPE;
      const int s0 = b * BSTEP;
      // wait: E rows for steps [s0, s0+128) published
      if (tid < 64) {
        while (true) {
          const int s1 = s0 + lane, s2 = s0 + 64 + lane;
          const int e1 = (s1 < T_STEPS)
              ? __hip_atomic_load(Edone + s1, __ATOMIC_RELAXED,
                                  __HIP_MEMORY_SCOPE_AGENT) : 1;
          const int e2 = (s2 < T_STEPS)
              ? __hip_atomic_load(Edone + s2, __ATOMIC_RELAXED,
                                  __HIP_MEMORY_SCOPE_AGENT) : 1;
          if (__all((e1 != 0) && (e2 != 0))) break;
          __builtin_amdgcn_s_sleep(8);
        }
      }
      const int cbase = j * 128;
      const int col0 = cbase + lane, col1 = cbase + 64 + lane;
      const bool cv0 = col0 < NV, cv1 = col1 < NV;   // col0 always valid here
      const float* e0p = emb + (size_t)(cv0 ? col0 : 0) * 1024;
      const float* e1p = emb + (size_t)(cv1 ? col1 : 0) * 1024;
      const float ob0 = cv0 ? out_b[col0] : 0.f;
      const float ob1 = cv1 ? out_b[col1] : 0.f;
      double acc0[16] = {}, acc1[16] = {};
      const int sstage = tid & 127, kstage = (tid >> 7) * 8;
      const double* esrc = Ering
          + (size_t)((s0 + sstage) & (ERING - 1)) * 1024 + kstage;
      for (int kt = 0; kt < 32; ++kt) {       // k-tiles of 32, ascending
        const int kb = kt * 32;
        __syncthreads();
        // stage E tile: SM[kj*128 + si] ; thread: si=tid&127, 8 consecutive k
        {
          const double* sp = esrc + kb;
#pragma unroll
          for (int q = 0; q < 8; ++q)
            SM[(kstage + q) * 128 + sstage] = sp[q];
        }
        __syncthreads();
#pragma unroll 2
        for (int kj = 0; kj < 32; kj += 4) {
          const float4 f0 = *(const float4*)(e0p + kb + kj);
          const float4 f1 = *(const float4*)(e1p + kb + kj);
          const float b0a[4] = {f0.x, f0.y, f0.z, f0.w};
          const float b1a[4] = {f1.x, f1.y, f1.z, f1.w};
#pragma unroll
          for (int q = 0; q < 4; ++q) {
            const double d0 = (double)b0a[q], d1 = (double)b1a[q];
            const double* ep = SM + (size_t)(kj + q) * 128 + wv * 16;
#pragma unroll
            for (int sp = 0; sp < 8; ++sp) {
              const double2 ev = *(const double2*)(ep + sp * 2);
              acc0[sp*2]   = fma(ev.x, d0, acc0[sp*2]);
              acc0[sp*2+1] = fma(ev.y, d0, acc0[sp*2+1]);
              acc1[sp*2]   = fma(ev.x, d1, acc1[sp*2]);
              acc1[sp*2+1] = fma(ev.y, d1, acc1[sp*2+1]);
            }
          }
        }
      }
      // epilogue: wave wv owns steps s0 + wv*16 + si
#pragma unroll
      for (int si = 0; si < 16; ++si) {
        const int s = s0 + wv * 16 + si;
        if (s < T_STEPS) {
          const int tgt = inputs[s + 1];
          const double lgd0 = acc0[si] + (double)ob0;
          const double lgd1 = acc1[si] + (double)ob1;
          float L1a = cv0 ? (float)lgd0 : -3e38f;
          int   i1a = cv0 ? col0 : 0x7FFFFFFF;
          float L2a = -3e38f; int i2a = 0x7FFFFFFF;
          float L1b = cv1 ? (float)lgd1 : -3e38f;
          int   i1b = cv1 ? col1 : 0x7FFFFFFF;
          float L2b = -3e38f; int i2b = 0x7FFFFFFF;
          float se = (cv0 ? expf((float)(lgd0 - 0.01)) : 0.f)
                   + (cv1 ? expf((float)(lgd1 - 0.01)) : 0.f);
          float tv = -INFINITY;
          if (cv0 && col0 == tgt) tv = (float)lgd0;
          if (cv1 && col1 == tgt) tv = (float)lgd1;
#pragma unroll
          for (int mk = 1; mk <= 32; mk <<= 1) {
            const float oL1a = __shfl_xor(L1a, mk, 64);
            const int   oi1a = __shfl_xor(i1a, mk, 64);
            const float oL2a = __shfl_xor(L2a, mk, 64);
            const int   oi2a = __shfl_xor(i2a, mk, 64);
            if (oL1a > L1a || (oL1a == L1a && oi1a < i1a)) { L2a = L1a; i2a = i1a; L1a = oL1a; i1a = oi1a; }
            else if (oL1a > L2a || (oL1a == L2a && oi1a < i2a)) { L2a = oL1a; i2a = oi1a; }
            if (oL2a > L1a || (oL2a == L1a && oi2a < i1a)) { L2a = L1a; i2a = i1a; L1a = oL2a; i1a = oi2a; }
            else if (oL2a > L2a || (oL2a == L2a && oi2a < i2a)) { L2a = oL2a; i2a = oi2a; }
            const float oL1b = __shfl_xor(L1b, mk, 64);
            const int   oi1b = __shfl_xor(i1b, mk, 64);
            const float oL2b = __shfl_xor(L2b, mk, 64);
            const int   oi2b = __shfl_xor(i2b, mk, 64);
            if (oL1b > L1b || (oL1b == L1b && oi1b < i1b)) { L2b = L1b; i2b = i1b; L1b = oL1b; i1b = oi1b; }
            else if (oL1b > L2b || (oL1b == L2b && oi1b < i2b)) { L2b = oL1b; i2b = oi1b; }
            if (oL2b > L1b || (oL2b == L1b && oi2b < i1b)) { L2b = L1b; i2b = i1b; L1b = oL2b; i1b = oi2b; }
            else if (oL2b > L2b || (oL2b == L2b && oi2b < i2b)) { L2b = oL2b; i2b = oi2b; }
            se += __shfl_xor(se, mk, 64);
            tv = fmaxf(tv, __shfl_xor(tv, mk, 64));
          }
          if (lane == 0) {
            float* cl = (float*)(candb + (size_t)s * TSB);
            int*   ci = (int*)(candb + (size_t)s * TSB + CANDI_OFF);
            const int cha = j * 2, chb = j * 2 + 1;
            cl[cha * 2]     = L1a;  ci[cha * 2]     = i1a;
            cl[cha * 2 + 1] = L2a;  ci[cha * 2 + 1] = i2a;
            cl[chb * 2]     = L1b;  ci[chb * 2]     = i1b;
            cl[chb * 2 + 1] = L2b;  ci[chb * 2 + 1] = i2b;
            atomicAdd(Psum + s, se);
            if (tv > -1e30f) Ttgt[s] = tv;
          }
        }
      }
      __syncthreads();     // E-tile reads + epilogue done
      if (tid == 0) atomicAdd(bcount + b, 1);
    }
  }
}

// --------- preds: np-faithful fp32 log_softmax quantized argmax -------------
__global__ __launch_bounds__(256) void k_preds(const char* __restrict__ candb,
                                               float* __restrict__ out) {
  __shared__ float sL[256];
  __shared__ int   sI[256];
  const int s = blockIdx.x;        // 0..1022
  const int tid = threadIdx.x;
  const float* candL = (const float*)(candb + (size_t)s * TSB);
  const int*   candI = (const int*)(candb + (size_t)s * TSB + CANDI_OFF);
  const int n = NCAND;             // 1564
  float m = -3e38f;
  for (int c = tid; c < n; c += 256) m = fmaxf(m, candL[c]);
  sL[tid] = m; __syncthreads();
  for (int st = 128; st > 0; st >>= 1) {
    if (tid < st) sL[tid] = fmaxf(sL[tid], sL[tid + st]);
    __syncthreads();
  }
  const float Lmax = sL[0];
  __syncthreads();
  float bq = -3e38f; int bi = 0x7FFFFFFF;
  for (int c = tid; c < n; c += 256) {
    const float L = candL[c];
    const int   v = candI[c];
    const float d = L - Lmax;              // Sterbenz-exact
    const float q = d - 10.8125f;          // fp32 bucket quantization
    if (q > bq || (q == bq && v < bi)) { bq = q; bi = v; }
  }
  sL[tid] = bq; sI[tid] = bi; __syncthreads();
  for (int st = 128; st > 0; st >>= 1) {
    if (tid < st) {
      if (sL[tid + st] > sL[tid] ||
          (sL[tid + st] == sL[tid] && sI[tid + st] < sI[tid])) {
        sL[tid] = sL[tid + st]; sI[tid] = sI[tid + st];
      }
    }
    __syncthreads();
  }
  if (tid == 0) out[2 + s] = (float)sI[0];
}

// ------------------------------------------------ final loss ----------------
__global__ __launch_bounds__(1024) void k_finish(const float* __restrict__ Psum,
                                                 const float* __restrict__ Ttgt,
                                                 float* __restrict__ out) {
  __shared__ double red[1024];
  const int s = threadIdx.x;
  double ls = 0.0;
  if (s < T_STEPS) ls = 0.01 + log((double)Psum[s]) - (double)Ttgt[s];
  red[s] = ls;
  __syncthreads();
  for (int st = 512; st > 0; st >>= 1) {
    if (s < st) red[s] += red[s + st];
    __syncthreads();
  }
  if (s == 0) out[0] = (float)red[0];
  if (s == 1) out[1] = 0.f;
}

// ----------------------------------------------------------------- launch ---
extern "C" void kernel_launch(void* const* d_in, const int* in_sizes, int n_in,
                              void* d_out, int out_size, void* d_ws, size_t ws_size,
                              hipStream_t stream) {
  const int*   inputs = (const int*)  d_in[0];
  const float* z      = (const float*)d_in[1];
  const float* emb    = (const float*)d_in[2];
  const float* out_b  = (const float*)d_in[3];
  const float* h2eW   = (const float*)d_in[4];
  const float* h2eb   = (const float*)d_in[5];
  const float* Wih    = (const float*)d_in[6];
  const float* Whh    = (const float*)d_in[7];
  const float* bih    = (const float*)d_in[8];
  const float* bhh    = (const float*)d_in[9];

  char* ws8 = (char*)d_ws;
  ull*    SA     = (ull*)ws8;                      // [0, 16K)
  ull*    SB     = (ull*)(ws8 + 16384);            // [16K, 32K)
  int*    done   = (int*)(ws8 + 32768);            // 512 B
  int*    prog   = (int*)(ws8 + 33280);            // 256 B
  int*    Edone  = (int*)(ws8 + 33536);            // 4 KiB
  int*    bcount = (int*)(ws8 + 37632);            // 64 B
  float*  Psum   = (float*)(ws8 + 40960);          // 4 KiB
  float*  Ttgt   = (float*)(ws8 + 45056);          // 4 KiB
  char*   GIb    = ws8 + 98304;                    // 24 MiB (GI + cand)
  double* GI     = (double*)GIb;
  double* XE     = (double*)(GIb + (24u << 20));   // 4 MiB: X then Ering
  double* H      = (double*)(GIb + (28u << 20));   // 8 MiB
  float*  out    = (float*)d_out;

  hipMemsetAsync(ws8, 0, 49152, stream);  // SA SB done prog Edone bcount Psum Ttgt

  k_gather<<<1024, 256, 0, stream>>>(inputs, emb, (float*)XE);
  k_gemm_ffd<<<dim3(48, 16), 256, 0, stream>>>((float*)XE, Wih, bih, GI,
                                               3072, KDIM);
  k_mega<<<NBLK, 512, 0, stream>>>(z, Whh, bhh, GI, H, SA, SB, done,
                                   prog, Edone, bcount, XE, h2eW, h2eb,
                                   emb, out_b, inputs, Psum, Ttgt, GIb);
  k_preds<<<T_STEPS, 256, 0, stream>>>(GIb, out);
  k_finish<<<1, 1024, 0, stream>>>(Psum, Ttgt, out);
}

// Round 15
// 9310.553 us; speedup vs baseline: 1.1201x; 1.1201x over previous
//
#include <hip/hip_runtime.h>
#include <math.h>

#define NV      50000
#define T_STEPS 1023
#define KDIM    1024
#define NCH     391     // 128-col logits chunks
#define TAU     4e-5f
typedef unsigned long long ull;

// ws layout (bytes):
//   [0,16K)     SA ull[2][1024]    [16K,32K) SB ull[2][1024]
//   [32K,+512)  done int[2][64]
//   [33280,+4K) Psum f32[1024]     [37376,+4K) Ttgt f32[1024]
//   [49152,+4M) X f32[1024][1024]
//   GIb = 49152+4M: GI f64[1024][3072] (24M); overlays after recur:
//       [+0,+8M)            E   f64[1024][1024]
//       [+8M,+11.06M)       candL f32[1024*782]
//       [+11.06M,+14.12M)   candI i32[1024*782]
//       [+14.12M,+18.12M)   Ef  f32[1024][1024]
//   [GIb+24M,+8M) H f64[1024][1024]
// total ~36.05 MiB

// ---------------------------------------------------------------- gather ----
__global__ __launch_bounds__(256) void k_gather(const int* __restrict__ inputs,
                                                const float* __restrict__ emb,
                                                float* __restrict__ X) {
  const int t = blockIdx.x;
  const int tid = threadIdx.x;
  float4 v = make_float4(0.f, 0.f, 0.f, 0.f);
  if (t < T_STEPS) {
    const int tok = (t == 0) ? 0 : inputs[t];
    v = *(const float4*)&emb[(size_t)tok * KDIM + tid * 4];
  }
  *(float4*)&X[(size_t)t * KDIM + tid * 4] = v;
}

// ---------------- NT GEMM: A f32 x B f32 -> C f64, fp64 accumulate ----------
__global__ __launch_bounds__(256) void k_gemm_ffd(const float* __restrict__ A,
                                                  const float* __restrict__ B,
                                                  const float* __restrict__ bias,
                                                  double* __restrict__ C,
                                                  int N, int K) {
  __shared__ float As[32][68];
  __shared__ float Bs[32][68];
  const int tid = threadIdx.x;
  const int bx = blockIdx.x, by = blockIdx.y;
  const int lr = tid >> 2;
  const int lk = (tid & 3) * 8;
  const float* Ap = A + (size_t)(by * 64 + lr) * K + lk;
  const float* Bp = B + (size_t)(bx * 64 + lr) * K + lk;
  const int r0 = (tid >> 4) * 4;
  const int c0 = (tid & 15) * 4;
  double acc[4][4] = {};
  for (int kc = 0; kc < K; kc += 32) {
    const float4 a0 = *(const float4*)(Ap + kc);
    const float4 a1 = *(const float4*)(Ap + kc + 4);
    const float4 b0 = *(const float4*)(Bp + kc);
    const float4 b1 = *(const float4*)(Bp + kc + 4);
    __syncthreads();
    As[lk+0][lr]=a0.x; As[lk+1][lr]=a0.y; As[lk+2][lr]=a0.z; As[lk+3][lr]=a0.w;
    As[lk+4][lr]=a1.x; As[lk+5][lr]=a1.y; As[lk+6][lr]=a1.z; As[lk+7][lr]=a1.w;
    Bs[lk+0][lr]=b0.x; Bs[lk+1][lr]=b0.y; Bs[lk+2][lr]=b0.z; Bs[lk+3][lr]=b0.w;
    Bs[lk+4][lr]=b1.x; Bs[lk+5][lr]=b1.y; Bs[lk+6][lr]=b1.z; Bs[lk+7][lr]=b1.w;
    __syncthreads();
#pragma unroll
    for (int kk = 0; kk < 32; ++kk) {
      const float4 av = *(const float4*)&As[kk][r0];
      const float4 bv = *(const float4*)&Bs[kk][c0];
      const double aa[4] = {av.x, av.y, av.z, av.w};
      const double bb[4] = {bv.x, bv.y, bv.z, bv.w};
#pragma unroll
      for (int i = 0; i < 4; ++i)
#pragma unroll
        for (int j = 0; j < 4; ++j)
          acc[i][j] = fma(aa[i], bb[j], acc[i][j]);
    }
  }
  const int row = by * 64 + r0;
  const int col = bx * 64 + c0;
#pragma unroll
  for (int i = 0; i < 4; ++i)
#pragma unroll
    for (int j = 0; j < 4; ++j)
      C[(size_t)(row + i) * N + col + j] = acc[i][j] + (double)bias[col + j];
}

// ------- NT GEMM: A f64 x B f32 -> C f64 (+ fp32 copy), fp64 accumulate -----
__global__ __launch_bounds__(256) void k_gemm_dfd(const double* __restrict__ A,
                                                  const float* __restrict__ B,
                                                  const float* __restrict__ bias,
                                                  double* __restrict__ C,
                                                  float* __restrict__ Cf,
                                                  int N, int K) {
  __shared__ double As[32][68];
  __shared__ float  Bs[32][68];
  const int tid = threadIdx.x;
  const int bx = blockIdx.x, by = blockIdx.y;
  const int lr = tid >> 2;
  const int lk = (tid & 3) * 8;
  const double* Ap = A + (size_t)(by * 64 + lr) * K + lk;
  const float*  Bp = B + (size_t)(bx * 64 + lr) * K + lk;
  const int r0 = (tid >> 4) * 4;
  const int c0 = (tid & 15) * 4;
  double acc[4][4] = {};
  for (int kc = 0; kc < K; kc += 32) {
    double ar[8];
#pragma unroll
    for (int q = 0; q < 8; ++q) ar[q] = Ap[kc + q];
    const float4 b0 = *(const float4*)(Bp + kc);
    const float4 b1 = *(const float4*)(Bp + kc + 4);
    __syncthreads();
#pragma unroll
    for (int q = 0; q < 8; ++q) As[lk + q][lr] = ar[q];
    Bs[lk+0][lr]=b0.x; Bs[lk+1][lr]=b0.y; Bs[lk+2][lr]=b0.z; Bs[lk+3][lr]=b0.w;
    Bs[lk+4][lr]=b1.x; Bs[lk+5][lr]=b1.y; Bs[lk+6][lr]=b1.z; Bs[lk+7][lr]=b1.w;
    __syncthreads();
#pragma unroll
    for (int kk = 0; kk < 32; ++kk) {
      const double aa[4] = {As[kk][r0+0], As[kk][r0+1], As[kk][r0+2], As[kk][r0+3]};
      const float4 bv = *(const float4*)&Bs[kk][c0];
      const double bb[4] = {bv.x, bv.y, bv.z, bv.w};
#pragma unroll
      for (int i = 0; i < 4; ++i)
#pragma unroll
        for (int j = 0; j < 4; ++j)
          acc[i][j] = fma(aa[i], bb[j], acc[i][j]);
    }
  }
  const int row = by * 64 + r0;
  const int col = bx * 64 + c0;
#pragma unroll
  for (int i = 0; i < 4; ++i)
#pragma unroll
    for (int j = 0; j < 4; ++j) {
      const double o = acc[i][j] + (double)bias[col + j];
      C [(size_t)(row + i) * N + col + j] = o;
      Cf[(size_t)(row + i) * N + col + j] = (float)o;
    }
}

// -------------------- persistent GRU recurrence (r9 exact) ------------------
__global__ __launch_bounds__(512, 2) void k_recur(const float* __restrict__ z,
                                                  const float* __restrict__ Whh,
                                                  const float* __restrict__ bhh,
                                                  const double* __restrict__ GI,
                                                  double* H, ull* SA, ull* SB,
                                                  int* done) {
  __shared__ double hs[1024];
  const int tid = threadIdx.x;
  const int w = tid >> 6, l = tid & 63;
  const int ibase = blockIdx.x * 16 + w * 2;
  float wreg[6][16];
#pragma unroll
  for (int il = 0; il < 2; ++il)
#pragma unroll
    for (int g = 0; g < 3; ++g) {
      const float* wp = Whh + (size_t)(g * 1024 + ibase + il) * 1024 + l;
#pragma unroll
      for (int m = 0; m < 16; ++m) wreg[il * 3 + g][m] = wp[m * 64];
    }
  double bh[6];
#pragma unroll
  for (int il = 0; il < 2; ++il)
#pragma unroll
    for (int g = 0; g < 3; ++g) bh[il * 3 + g] = (double)bhh[g * 1024 + ibase + il];

  hs[tid]       = (double)z[tid];
  hs[tid + 512] = (double)z[tid + 512];
  double gi[6];
#pragma unroll
  for (int il = 0; il < 2; ++il)
#pragma unroll
    for (int g = 0; g < 3; ++g) gi[il * 3 + g] = GI[g * 1024 + ibase + il];
  __syncthreads();

  for (int t = 0; t < T_STEPS; ++t) {
    const bool more = (t + 1 < T_STEPS);
    const int p = t & 1;
    const bool gate = more && (t >= 2);
    int dv = 0x7FFFFFFF;
    if (gate && tid < 64)
      dv = __hip_atomic_load(done + p * 64 + tid,
                             __ATOMIC_RELAXED, __HIP_MEMORY_SCOPE_AGENT);
    double s[6] = {0.0, 0.0, 0.0, 0.0, 0.0, 0.0};
#pragma unroll
    for (int m = 0; m < 16; ++m) {
      const double hv = hs[l + 64 * m];
#pragma unroll
      for (int rr = 0; rr < 6; ++rr) s[rr] = fma((double)wreg[rr][m], hv, s[rr]);
    }
#pragma unroll
    for (int rr = 0; rr < 6; ++rr) {
      double v = s[rr];
#pragma unroll
      for (int mk = 32; mk >= 1; mk >>= 1) v += __shfl_xor(v, mk, 64);
      s[rr] = v;
    }
    double hn = 0.0;
    if (l < 2) {
      const int il = l;
      const double r  = 1.0 / (1.0 + exp(-(gi[il*3+0] + s[il*3+0] + bh[il*3+0])));
      const double zg = 1.0 / (1.0 + exp(-(gi[il*3+1] + s[il*3+1] + bh[il*3+1])));
      const double n  = tanh(gi[il*3+2] + r * (s[il*3+2] + bh[il*3+2]));
      hn = (1.0 - zg) * n + zg * hs[ibase + l];
    }
    double gin[6] = {0.0, 0.0, 0.0, 0.0, 0.0, 0.0};
    if (more) {
      const double* gp = GI + (size_t)(t + 1) * 3072;
#pragma unroll
      for (int il = 0; il < 2; ++il)
#pragma unroll
        for (int g = 0; g < 3; ++g) gin[il * 3 + g] = gp[g * 1024 + ibase + il];
    }
    if (gate && tid < 64) {
      while (!__all(dv >= t - 1)) {
        __builtin_amdgcn_s_sleep(1);
        dv = __hip_atomic_load(done + p * 64 + tid,
                               __ATOMIC_RELAXED, __HIP_MEMORY_SCOPE_AGENT);
      }
    }
    __syncthreads();
    if (l < 2) {
      const int gidx = ibase + l;
      __hip_atomic_store(H + (size_t)t * 1024 + gidx, hn,
                         __ATOMIC_RELAXED, __HIP_MEMORY_SCOPE_AGENT);
      if (more) {
        const ull hb  = (ull)__double_as_longlong(hn);
        const ull tag = ((ull)(t + 1)) << 32;
        __hip_atomic_store(SA + p * 1024 + gidx, tag | (hb >> 32),
                           __ATOMIC_RELAXED, __HIP_MEMORY_SCOPE_AGENT);
        __hip_atomic_store(SB + p * 1024 + gidx, tag | (hb & 0xFFFFFFFFull),
                           __ATOMIC_RELAXED, __HIP_MEMORY_SCOPE_AGENT);
      }
    }
    if (more) {
      const ull want = (ull)(t + 1);
      ull a0, b0, a1, b1;
      while (true) {
        a0 = __hip_atomic_load(SA + p * 1024 + tid,
                               __ATOMIC_RELAXED, __HIP_MEMORY_SCOPE_AGENT);
        b0 = __hip_atomic_load(SB + p * 1024 + tid,
                               __ATOMIC_RELAXED, __HIP_MEMORY_SCOPE_AGENT);
        if ((a0 >> 32) >= want && (b0 >> 32) >= want) break;
        __builtin_amdgcn_s_sleep(1);
      }
      while (true) {
        a1 = __hip_atomic_load(SA + p * 1024 + tid + 512,
                               __ATOMIC_RELAXED, __HIP_MEMORY_SCOPE_AGENT);
        b1 = __hip_atomic_load(SB + p * 1024 + tid + 512,
                               __ATOMIC_RELAXED, __HIP_MEMORY_SCOPE_AGENT);
        if ((a1 >> 32) >= want && (b1 >> 32) >= want) break;
        __builtin_amdgcn_s_sleep(1);
      }
      hs[tid]       = __longlong_as_double((long long)
                        (((a0 & 0xFFFFFFFFull) << 32) | (b0 & 0xFFFFFFFFull)));
      hs[tid + 512] = __longlong_as_double((long long)
                        (((a1 & 0xFFFFFFFFull) << 32) | (b1 & 0xFFFFFFFFull)));
      __syncthreads();
      if (tid == 0)
        __hip_atomic_store(done + p * 64 + blockIdx.x, t + 1,
                           __ATOMIC_RELAXED, __HIP_MEMORY_SCOPE_AGENT);
#pragma unroll
      for (int q = 0; q < 6; ++q) gi[q] = gin[q];
    }
  }
}

// ---- logits: fp32 GEMM (128x128 tile) + exact fp64 rescore of band ---------
// Selection: per 128-col chunk, cols with approx >= chunkmax - TAU are
// rescored with the bit-identical fp64 ascending-k chain (same bits as the
// passing full-fp64 rounds). Only cols within one fp32 bucket (9.5e-7) of
// their chunk max can affect the global quantized argmax; fp32 GEMM error
// bound <= ~9e-6 << TAU/2. Psum/Ttgt use approx values (loss tol 926).
__global__ __launch_bounds__(256) void k_logits_f32(
    const float* __restrict__ Ef, const double* __restrict__ E64,
    const float* __restrict__ emb, const float* __restrict__ out_b,
    const int* __restrict__ inputs,
    float* __restrict__ candL, int* __restrict__ candI,
    float* __restrict__ Psum, float* __restrict__ Ttgt) {
  __shared__ float As[128][33];
  __shared__ float Bs[32][132];
  __shared__ int   WLs[2048];
  __shared__ int   WLv[2048];
  __shared__ float Lr[2048];
  __shared__ int   wcnt;
  const int tid = threadIdx.x;
  const int bx = blockIdx.x, by = blockIdx.y;
  const int arow = tid >> 1, akk = (tid & 1) * 16;
  const float* Ap = Ef + (size_t)(by * 128 + arow) * KDIM + akk;
  const int bcol = tid >> 1, bk = (tid & 1) * 16;
  const int brow = bx * 128 + bcol;
  const float* Bp = emb + (size_t)brow * KDIM + bk;
  const bool bvalid = brow < NV;
  const int r0 = (tid >> 4) * 8;
  const int c0 = (tid & 15) * 8;
  float acc[8][8] = {};
  for (int kc = 0; kc < KDIM; kc += 32) {
    float4 ar[4], br[4];
#pragma unroll
    for (int q = 0; q < 4; ++q) {
      ar[q] = *(const float4*)(Ap + kc + q * 4);
      br[q] = bvalid ? *(const float4*)(Bp + kc + q * 4)
                     : make_float4(0.f, 0.f, 0.f, 0.f);
    }
    __syncthreads();
#pragma unroll
    for (int q = 0; q < 4; ++q) {
      As[arow][akk + q*4 + 0] = ar[q].x;
      As[arow][akk + q*4 + 1] = ar[q].y;
      As[arow][akk + q*4 + 2] = ar[q].z;
      As[arow][akk + q*4 + 3] = ar[q].w;
      Bs[bk + q*4 + 0][bcol] = br[q].x;
      Bs[bk + q*4 + 1][bcol] = br[q].y;
      Bs[bk + q*4 + 2][bcol] = br[q].z;
      Bs[bk + q*4 + 3][bcol] = br[q].w;
    }
    __syncthreads();
#pragma unroll 4
    for (int kk = 0; kk < 32; ++kk) {
      float aa[8];
#pragma unroll
      for (int i = 0; i < 8; ++i) aa[i] = As[r0 + i][kk];
      const float4 bv0 = *(const float4*)&Bs[kk][c0];
      const float4 bv1 = *(const float4*)&Bs[kk][c0 + 4];
      const float bb[8] = {bv0.x, bv0.y, bv0.z, bv0.w,
                           bv1.x, bv1.y, bv1.z, bv1.w};
#pragma unroll
      for (int i = 0; i < 8; ++i)
#pragma unroll
        for (int j = 0; j < 8; ++j)
          acc[i][j] = fmaf(aa[i], bb[j], acc[i][j]);
    }
  }
  // ---------------- epilogue with banded exact rescore ----------------------
  const int colb = bx * 128 + c0;
  float ob[8];
#pragma unroll
  for (int j = 0; j < 8; ++j) {
    const int v = colb + j;
    ob[j] = (v < NV) ? out_b[v] : 0.f;
  }
#pragma unroll
  for (int i = 0; i < 8; ++i) {
    const int s = by * 128 + r0 + i;
    const bool valid = (s < T_STEPS);
    if (tid == 0) wcnt = 0;
    __syncthreads();
    float af[8];
    float M = -3e38f;
#pragma unroll
    for (int j = 0; j < 8; ++j) {
      const int v = colb + j;
      af[j] = (v < NV) ? acc[i][j] + ob[j] : -3e38f;
      M = fmaxf(M, af[j]);
    }
#pragma unroll
    for (int mk = 1; mk <= 8; mk <<= 1) M = fmaxf(M, __shfl_xor(M, mk, 64));
    int myidx[8];
#pragma unroll
    for (int j = 0; j < 8; ++j) {
      const int v = colb + j;
      myidx[j] = -1;
      if (valid && v < NV && af[j] >= M - TAU) {
        const int ix = atomicAdd(&wcnt, 1);
        myidx[j] = ix;
        WLs[ix] = s;
        WLv[ix] = v;
      }
    }
    __syncthreads();
    const int nw = wcnt;
    for (int wi = tid; wi < nw; wi += 256) {
      const int ss = WLs[wi], vv = WLv[wi];
      const double* Er = E64 + (size_t)ss * KDIM;
      const float*  br2 = emb + (size_t)vv * KDIM;
      double d = 0.0;
#pragma unroll 4
      for (int k = 0; k < KDIM; ++k) d = fma(Er[k], (double)br2[k], d);
      Lr[wi] = (float)(d + (double)out_b[vv]);
    }
    __syncthreads();
    const int tgt = valid ? inputs[s + 1] : -1;
    float L1 = -3e38f, L2 = -3e38f;
    int   i1 = 0x7FFFFFFF, i2 = 0x7FFFFFFF;
    float se = 0.f, tv = -INFINITY;
#pragma unroll
    for (int j = 0; j < 8; ++j) {
      const int v = colb + j;
      if (v < NV) {
        se += expf(af[j] - 0.01f);
        if (v == tgt) tv = af[j];
        const float L = (myidx[j] >= 0) ? Lr[myidx[j]] : -3e38f;
        if (L > L1 || (L == L1 && v < i1)) { L2 = L1; i2 = i1; L1 = L; i1 = v; }
        else if (L > L2 || (L == L2 && v < i2)) { L2 = L; i2 = v; }
      }
    }
#pragma unroll
    for (int mk = 1; mk <= 8; mk <<= 1) {
      const float oL1 = __shfl_xor(L1, mk, 64); const int oi1 = __shfl_xor(i1, mk, 64);
      const float oL2 = __shfl_xor(L2, mk, 64); const int oi2 = __shfl_xor(i2, mk, 64);
      if (oL1 > L1 || (oL1 == L1 && oi1 < i1)) { L2 = L1; i2 = i1; L1 = oL1; i1 = oi1; }
      else if (oL1 > L2 || (oL1 == L2 && oi1 < i2)) { L2 = oL1; i2 = oi1; }
      if (oL2 > L1 || (oL2 == L1 && oi2 < i1)) { L2 = L1; i2 = i1; L1 = oL2; i1 = oi2; }
      else if (oL2 > L2 || (oL2 == L2 && oi2 < i2)) { L2 = oL2; i2 = oi2; }
      se += __shfl_xor(se, mk, 64);
      tv = fmaxf(tv, __shfl_xor(tv, mk, 64));
    }
    if (((tid & 15) == 0) && valid) {
      const size_t p = (size_t)s * (2 * NCH) + 2 * bx;
      candL[p] = L1;     candI[p] = i1;
      candL[p + 1] = L2; candI[p + 1] = i2;
      atomicAdd(&Psum[s], se);
      if (tv > -1e30f) Ttgt[s] = tv;
    }
    __syncthreads();
  }
}

// --------- preds: np-faithful fp32 log_softmax quantized argmax -------------
__global__ __launch_bounds__(256) void k_preds(const float* __restrict__ candL,
                                               const int* __restrict__ candI,
                                               float* __restrict__ out) {
  __shared__ float sL[256];
  __shared__ int   sI[256];
  const int s = blockIdx.x;
  const int tid = threadIdx.x;
  const int n = 2 * NCH;           // 782
  const size_t base = (size_t)s * n;
  float m = -3e38f;
  for (int c = tid; c < n; c += 256) m = fmaxf(m, candL[base + c]);
  sL[tid] = m; __syncthreads();
  for (int st = 128; st > 0; st >>= 1) {
    if (tid < st) sL[tid] = fmaxf(sL[tid], sL[tid + st]);
    __syncthreads();
  }
  const float Lmax = sL[0];
  __syncthreads();
  float bq = -3e38f; int bi = 0x7FFFFFFF;
  for (int c = tid; c < n; c += 256) {
    const float L = candL[base + c];
    const int   v = candI[base + c];
    const float d = L - Lmax;
    const float q = d - 10.8125f;
    if (q > bq || (q == bq && v < bi)) { bq = q; bi = v; }
  }
  sL[tid] = bq; sI[tid] = bi; __syncthreads();
  for (int st = 128; st > 0; st >>= 1) {
    if (tid < st) {
      if (sL[tid + st] > sL[tid] ||
          (sL[tid + st] == sL[tid] && sI[tid + st] < sI[tid])) {
        sL[tid] = sL[tid + st]; sI[tid] = sI[tid + st];
      }
    }
    __syncthreads();
  }
  if (tid == 0) out[2 + s] = (float)sI[0];
}

// ------------------------------------------------ final loss ----------------
__global__ __launch_bounds__(1024) void k_finish(const float* __restrict__ Psum,
                                                 const float* __restrict__ Ttgt,
                                                 float* __restrict__ out) {
  __shared__ double red[1024];
  const int s = threadIdx.x;
  double ls = 0.0;
  if (s < T_STEPS) ls = 0.01 + log((double)Psum[s]) - (double)Ttgt[s];
  red[s] = ls;
  __syncthreads();
  for (int st = 512; st > 0; st >>= 1) {
    if (s < st) red[s] += red[s + st];
    __syncthreads();
  }
  if (s == 0) out[0] = (float)red[0];
  if (s == 1) out[1] = 0.f;
}

// ----------------------------------------------------------------- launch ---
extern "C" void kernel_launch(void* const* d_in, const int* in_sizes, int n_in,
                              void* d_out, int out_size, void* d_ws, size_t ws_size,
                              hipStream_t stream) {
  const int*   inputs = (const int*)  d_in[0];
  const float* z      = (const float*)d_in[1];
  const float* emb    = (const float*)d_in[2];
  const float* out_b  = (const float*)d_in[3];
  const float* h2eW   = (const float*)d_in[4];
  const float* h2eb   = (const float*)d_in[5];
  const float* Wih    = (const float*)d_in[6];
  const float* Whh    = (const float*)d_in[7];
  const float* bih    = (const float*)d_in[8];
  const float* bhh    = (const float*)d_in[9];

  char* ws8 = (char*)d_ws;
  ull*    SA    = (ull*)ws8;                             // [0, 16K)
  ull*    SB    = (ull*)(ws8 + 16384);                   // [16K, 32K)
  int*    done  = (int*)(ws8 + 32768);                   // 512 B
  float*  Psum  = (float*)(ws8 + 33280);                 // 4 KiB
  float*  Ttgt  = (float*)(ws8 + 37376);                 // 4 KiB
  float*  X     = (float*)(ws8 + 49152);                 // 4 MiB
  char*   GIb   = ws8 + 49152 + (4u << 20);              // 24 MiB region
  double* GI    = (double*)GIb;
  double* E     = GI;                                    // 8 MiB overlay
  float*  candL = (float*)(GIb + (8u << 20));            // 3.06 MiB
  int*    candI = (int*)  (GIb + (8u << 20) + 3211264);  // 3.06 MiB
  float*  Ef    = (float*)(GIb + (8u << 20) + 6422528);  // 4 MiB
  double* H     = (double*)(GIb + (24u << 20));          // 8 MiB
  float*  out   = (float*)d_out;

  hipMemsetAsync(ws8, 0, 49152, stream);   // SA + SB + done + Psum + Ttgt

  k_gather<<<1024, 256, 0, stream>>>(inputs, emb, X);
  k_gemm_ffd<<<dim3(48, 16), 256, 0, stream>>>(X, Wih, bih, GI, 3072, KDIM);
  k_recur<<<64, 512, 0, stream>>>(z, Whh, bhh, GI, H, SA, SB, done);
  k_gemm_dfd<<<dim3(16, 16), 256, 0, stream>>>(H, h2eW, h2eb, E, Ef, KDIM, KDIM);
  k_logits_f32<<<dim3(NCH, 8), 256, 0, stream>>>(Ef, E, emb, out_b, inputs,
                                                 candL, candI, Psum, Ttgt);
  k_preds<<<T_STEPS, 256, 0, stream>>>(candL, candI, out);
  k_finish<<<1, 1024, 0, stream>>>(Psum, Ttgt, out);
}